// Round 1
// baseline (1358.600 us; speedup 1.0000x reference)
//
#include <hip/hip_runtime.h>
#include <cstdint>
#include <cstddef>

// GraphCluster: 3-layer GCN + assign head on a 100K-node / 1.6M-edge random graph.
// Strategy: device-built dst-CSR (histogram -> 1-block scan -> atomic fill),
// fp32 LDS-tiled GEMMs (no fp32 MFMA on CDNA4), per-node wave gather-reduce.

// ---------------------------------------------------------------- CSR build
__global__ __launch_bounds__(256) void count_edges_k(const int* __restrict__ dst, int E,
                                                     int* __restrict__ cnt) {
  int idx = blockIdx.x * blockDim.x + threadIdx.x;
  int stride = gridDim.x * blockDim.x;
  for (int e = idx; e < E; e += stride) atomicAdd(&cnt[dst[e]], 1);
}

__global__ __launch_bounds__(256) void dinv_k(const int* __restrict__ cnt,
                                              float* __restrict__ dinv, int N) {
  int i = blockIdx.x * blockDim.x + threadIdx.x;
  if (i < N) dinv[i] = rsqrtf((float)(cnt[i] + 1));  // +1 self-loop; always >= 1
}

__global__ __launch_bounds__(1024) void scan_k(const int* __restrict__ cnt,
                                               int* __restrict__ rowptr,
                                               int* __restrict__ cursor, int N) {
  __shared__ int sums[1024];
  int t = threadIdx.x;
  int chunk = (N + 1023) >> 10;
  int beg = t * chunk;
  int end = min(beg + chunk, N);
  int s = 0;
  for (int i = beg; i < end; ++i) s += cnt[i];
  sums[t] = s;
  __syncthreads();
  for (int off = 1; off < 1024; off <<= 1) {
    int v = sums[t];
    int w = (t >= off) ? sums[t - off] : 0;
    __syncthreads();
    sums[t] = v + w;
    __syncthreads();
  }
  int run = (t == 0) ? 0 : sums[t - 1];
  for (int i = beg; i < end; ++i) {
    rowptr[i] = run;
    cursor[i] = run;
    run += cnt[i];
  }
  if (t == 1023) rowptr[N] = sums[1023];
}

__global__ __launch_bounds__(256) void fill_k(const int* __restrict__ src,
                                              const int* __restrict__ dst, int E,
                                              int* __restrict__ cursor, int* __restrict__ col) {
  int idx = blockIdx.x * blockDim.x + threadIdx.x;
  int stride = gridDim.x * blockDim.x;
  for (int e = idx; e < E; e += stride) {
    int d = dst[e];
    int pos = atomicAdd(&cursor[d], 1);
    col[pos] = src[e];
  }
}

// ---------------------------------------------------------------- GEMMs (fp32, VALU)
// out[N,128] = A[N,128] @ W[128,128] (+bias) (sigmoid optional).
// 64 rows/block, 256 threads, 8x4 micro-tile. A staged transposed (pad 68 so
// At rows are 16B-aligned for b128 reads); inner loop = 3x ds_read_b128 + 32 FMA.
template <bool SIG>
__global__ __launch_bounds__(256) void gemm128_k(const float* __restrict__ A,
                                                 const float* __restrict__ W,
                                                 const float* __restrict__ bias,
                                                 float* __restrict__ out, int N) {
  __shared__ float At[64][68];    // [k][row], 17.4 KB
  __shared__ float Wl[64][128];   // 32 KB
  const int tid = threadIdx.x;
  const int r0 = blockIdx.x * 64;
  const int cg = (tid & 31) * 4;  // 32 col-groups x 4 = 128
  const int rg = (tid >> 5) * 8;  // 8 row-groups x 8 = 64
  float acc[8][4];
#pragma unroll
  for (int r = 0; r < 8; ++r)
#pragma unroll
    for (int c = 0; c < 4; ++c) acc[r][c] = 0.f;

  for (int kt = 0; kt < 128; kt += 64) {
    if (kt) __syncthreads();
    // stage A tile transposed: 64 rows x 64 k = 1024 float4
#pragma unroll
    for (int idx = tid; idx < 1024; idx += 256) {
      int rr = idx >> 4;
      int k4 = (idx & 15) << 2;
      float4 v = make_float4(0.f, 0.f, 0.f, 0.f);
      int grow = r0 + rr;
      if (grow < N) v = *(const float4*)(A + (size_t)grow * 128 + kt + k4);
      At[k4 + 0][rr] = v.x;
      At[k4 + 1][rr] = v.y;
      At[k4 + 2][rr] = v.z;
      At[k4 + 3][rr] = v.w;
    }
    // stage W tile: 64 k x 128 cols = 2048 float4
#pragma unroll
    for (int idx = tid; idx < 2048; idx += 256) {
      int kk = idx >> 5;
      int c4 = (idx & 31) << 2;
      *(float4*)&Wl[kk][c4] = *(const float4*)(W + (size_t)(kt + kk) * 128 + c4);
    }
    __syncthreads();
#pragma unroll 8
    for (int k = 0; k < 64; ++k) {
      float4 a0 = *(const float4*)&At[k][rg];
      float4 a1 = *(const float4*)&At[k][rg + 4];
      float4 b = *(const float4*)&Wl[k][cg];
      float av[8] = {a0.x, a0.y, a0.z, a0.w, a1.x, a1.y, a1.z, a1.w};
      float bv[4] = {b.x, b.y, b.z, b.w};
#pragma unroll
      for (int r = 0; r < 8; ++r)
#pragma unroll
        for (int c = 0; c < 4; ++c) acc[r][c] = fmaf(av[r], bv[c], acc[r][c]);
    }
  }
  float bv[4] = {0.f, 0.f, 0.f, 0.f};
  if (bias) {
    float4 b4 = *(const float4*)(bias + cg);
    bv[0] = b4.x; bv[1] = b4.y; bv[2] = b4.z; bv[3] = b4.w;
  }
#pragma unroll
  for (int r = 0; r < 8; ++r) {
    int grow = r0 + rg + r;
    if (grow < N) {
      float t0 = acc[r][0] + bv[0];
      float t1 = acc[r][1] + bv[1];
      float t2 = acc[r][2] + bv[2];
      float t3 = acc[r][3] + bv[3];
      if (SIG) {
        t0 = 1.f / (1.f + __expf(-t0));
        t1 = 1.f / (1.f + __expf(-t1));
        t2 = 1.f / (1.f + __expf(-t2));
        t3 = 1.f / (1.f + __expf(-t3));
      }
      *(float4*)(out + (size_t)grow * 128 + cg) = make_float4(t0, t1, t2, t3);
    }
  }
}

// out[N,16] = A[N,128] @ W[128,16]  (assign head, bias added in aggregation)
__global__ __launch_bounds__(256) void gemm16_k(const float* __restrict__ A,
                                                const float* __restrict__ W,
                                                float* __restrict__ out, int N) {
  __shared__ float At[128][68];  // 34.8 KB
  __shared__ float Wl[128][16];  // 8 KB
  const int tid = threadIdx.x;
  const int r0 = blockIdx.x * 64;
  const int colc = tid & 15;
  const int rowg = (tid >> 4) * 4;  // 16 groups x 4 = 64 rows
  for (int idx = tid; idx < 2048; idx += 256) {
    int rr = idx >> 5;
    int k4 = (idx & 31) << 2;
    float4 v = make_float4(0.f, 0.f, 0.f, 0.f);
    int grow = r0 + rr;
    if (grow < N) v = *(const float4*)(A + (size_t)grow * 128 + k4);
    At[k4 + 0][rr] = v.x;
    At[k4 + 1][rr] = v.y;
    At[k4 + 2][rr] = v.z;
    At[k4 + 3][rr] = v.w;
  }
  for (int idx = tid; idx < 512; idx += 256) {
    int kk = idx >> 2;
    int c4 = (idx & 3) << 2;
    *(float4*)&Wl[kk][c4] = *(const float4*)(W + (size_t)kk * 16 + c4);
  }
  __syncthreads();
  float acc[4] = {0.f, 0.f, 0.f, 0.f};
#pragma unroll 8
  for (int k = 0; k < 128; ++k) {
    float4 a = *(const float4*)&At[k][rowg];
    float b = Wl[k][colc];
    acc[0] = fmaf(a.x, b, acc[0]);
    acc[1] = fmaf(a.y, b, acc[1]);
    acc[2] = fmaf(a.z, b, acc[2]);
    acc[3] = fmaf(a.w, b, acc[3]);
  }
#pragma unroll
  for (int r = 0; r < 4; ++r) {
    int grow = r0 + rowg + r;
    if (grow < N) out[(size_t)grow * 16 + colc] = acc[r];
  }
}

// ---------------------------------------------------------------- aggregation
// out[i] = b + dinv[i] * ( sum_{e: dst=i} dinv[src_e]*xw[src_e] + dinv[i]*xw[i] )
// One wave per node; each lane holds float2 of the 128-dim row.
__global__ __launch_bounds__(256) void agg128_k(const float* __restrict__ xw,
                                                const int* __restrict__ rowptr,
                                                const int* __restrict__ col,
                                                const float* __restrict__ dinv,
                                                const float* __restrict__ bias,
                                                float* __restrict__ out, int N) {
  int node = blockIdx.x * 4 + (threadIdx.x >> 6);
  if (node >= N) return;
  int lane = threadIdx.x & 63;
  int beg = rowptr[node];
  int end = rowptr[node + 1];
  float di = dinv[node];
  float2 sv = *(const float2*)(xw + (size_t)node * 128 + lane * 2);
  float ax = sv.x * di;  // self-loop term (di * xw[i]); whole sum scaled by di at end
  float ay = sv.y * di;
  for (int e = beg; e < end; ++e) {
    int s = col[e];          // wave-uniform -> scalar load
    float w = dinv[s];       // wave-uniform -> scalar load
    float2 v = *(const float2*)(xw + (size_t)s * 128 + lane * 2);
    ax = fmaf(v.x, w, ax);
    ay = fmaf(v.y, w, ay);
  }
  float2 bb = *(const float2*)(bias + lane * 2);
  *(float2*)(out + (size_t)node * 128 + lane * 2) =
      make_float2(fmaf(ax, di, bb.x), fmaf(ay, di, bb.y));
}

// 16-wide variant: one wave per node, 4 edges in flight (lane = j*16 + f)
__global__ __launch_bounds__(256) void agg16_k(const float* __restrict__ xw,
                                               const int* __restrict__ rowptr,
                                               const int* __restrict__ col,
                                               const float* __restrict__ dinv,
                                               const float* __restrict__ bias,
                                               float* __restrict__ out, int N) {
  int node = blockIdx.x * 4 + (threadIdx.x >> 6);
  if (node >= N) return;
  int lane = threadIdx.x & 63;
  int f = lane & 15;
  int j = lane >> 4;
  int beg = rowptr[node];
  int end = rowptr[node + 1];
  float di = dinv[node];
  float acc = 0.f;
  for (int e = beg + j; e < end; e += 4) {
    int s = col[e];
    acc = fmaf(xw[(size_t)s * 16 + f], dinv[s], acc);
  }
  acc += __shfl_xor(acc, 16, 64);
  acc += __shfl_xor(acc, 32, 64);
  float o = fmaf(acc + xw[(size_t)node * 16 + f] * di, di, bias[f]);
  if (j == 0) out[(size_t)node * 16 + f] = o;
}

// ---------------------------------------------------------------- launch
extern "C" void kernel_launch(void* const* d_in, const int* in_sizes, int n_in,
                              void* d_out, int out_size, void* d_ws, size_t ws_size,
                              hipStream_t stream) {
  const int* adj = (const int*)d_in[0];
  const float* X = (const float*)d_in[1];
  const float* fc1_W = (const float*)d_in[2];
  const float* fc1_b = (const float*)d_in[3];
  const float* fc2_W = (const float*)d_in[4];
  const float* fc2_b = (const float*)d_in[5];
  const float* gcn_W = (const float*)d_in[6];
  const float* gcn_b = (const float*)d_in[7];
  const float* assign_W = (const float*)d_in[8];
  const float* assign_b = (const float*)d_in[9];
  const int E = in_sizes[0] / 2;
  const int N = in_sizes[1] / 128;
  const int* src = adj;
  const int* dst = adj + E;

  char* ws = (char*)d_ws;
  size_t off = 0;
  auto alloc = [&](size_t bytes) {
    void* p = ws + off;
    off = (off + bytes + 511) & ~(size_t)511;
    return p;
  };
  float* P = (float*)alloc((size_t)N * 128 * 4);      // 51.2 MB
  float* Q = (float*)alloc((size_t)N * 128 * 4);      // 51.2 MB
  int* cnt = (int*)alloc((size_t)N * 4);
  float* dinv = (float*)alloc((size_t)N * 4);
  int* rowptr = (int*)alloc((size_t)(N + 1) * 4);
  int* cursor = (int*)alloc((size_t)N * 4);
  int* col = (int*)alloc((size_t)E * 4);              // 6.4 MB
  float* S = P;  // assign xw [N,16] reuses P (free by then)

  hipMemsetAsync(cnt, 0, (size_t)N * 4, stream);
  count_edges_k<<<2048, 256, 0, stream>>>(dst, E, cnt);
  dinv_k<<<(N + 255) / 256, 256, 0, stream>>>(cnt, dinv, N);
  scan_k<<<1, 1024, 0, stream>>>(cnt, rowptr, cursor, N);
  fill_k<<<2048, 256, 0, stream>>>(src, dst, E, cursor, col);

  int gb = (N + 63) / 64;
  int ab = (N + 3) / 4;
  gemm128_k<true><<<gb, 256, 0, stream>>>(X, fc1_W, fc1_b, P, N);
  gemm128_k<true><<<gb, 256, 0, stream>>>(P, fc2_W, fc2_b, Q, N);
  for (int l = 0; l < 3; ++l) {
    gemm128_k<false><<<gb, 256, 0, stream>>>(Q, gcn_W + (size_t)l * 128 * 128, nullptr, P, N);
    agg128_k<<<ab, 256, 0, stream>>>(P, rowptr, col, dinv, gcn_b + (size_t)l * 128, Q, N);
  }
  gemm16_k<<<gb, 256, 0, stream>>>(Q, assign_W, S, N);
  agg16_k<<<ab, 256, 0, stream>>>(S, rowptr, col, dinv, assign_b, (float*)d_out, N);
}

// Round 2
// 1164.717 us; speedup vs baseline: 1.1665x; 1.1665x over previous
//
#include <hip/hip_runtime.h>
#include <cstdint>
#include <cstddef>

// GraphCluster: 3-layer GCN + assign head on a 100K-node / 1.6M-edge random graph.
// R1: replaced 229us single-block scan with 3-phase hierarchical scan (~10us).

#define SCAN_CHUNK 2048

// ---------------------------------------------------------------- CSR build
__global__ __launch_bounds__(256) void count_edges_k(const int* __restrict__ dst, int E,
                                                     int* __restrict__ cnt) {
  int idx = blockIdx.x * blockDim.x + threadIdx.x;
  int stride = gridDim.x * blockDim.x;
  for (int e = idx; e < E; e += stride) atomicAdd(&cnt[dst[e]], 1);
}

__global__ __launch_bounds__(256) void dinv_k(const int* __restrict__ cnt,
                                              float* __restrict__ dinv, int N) {
  int i = blockIdx.x * blockDim.x + threadIdx.x;
  if (i < N) dinv[i] = rsqrtf((float)(cnt[i] + 1));  // +1 self-loop; always >= 1
}

// Phase A: per-block (2048-elem) sums.
__global__ __launch_bounds__(256) void scan_partial_k(const int* __restrict__ cnt, int N,
                                                      int* __restrict__ bsum) {
  __shared__ int red[256];
  int b = blockIdx.x, t = threadIdx.x;
  int base = b * SCAN_CHUNK + t * 8;
  int s = 0;
#pragma unroll
  for (int i = 0; i < 8; ++i) {
    int idx = base + i;
    if (idx < N) s += cnt[idx];
  }
  red[t] = s;
  __syncthreads();
  for (int off = 128; off > 0; off >>= 1) {
    if (t < off) red[t] += red[t + off];
    __syncthreads();
  }
  if (t == 0) bsum[b] = red[0];
}

// Phase B: exclusive scan of block sums (single 64-lane wave, lane-chunked).
__global__ __launch_bounds__(64) void scan_bsum_k(int* __restrict__ bsum, int NB) {
  int lane = threadIdx.x;
  int per = (NB + 63) >> 6;
  int beg = lane * per;
  int end = min(beg + per, NB);
  int s = 0;
  for (int i = beg; i < end; ++i) s += bsum[i];
  int ps = s;
  for (int off = 1; off < 64; off <<= 1) {
    int u = __shfl_up(ps, off, 64);
    if (lane >= off) ps += u;
  }
  int run = ps - s;  // exclusive prefix of this lane's chunk
  for (int i = beg; i < end; ++i) {
    int c = bsum[i];
    bsum[i] = run;
    run += c;
  }
}

// Phase C: block-local scan + global offset -> rowptr, cursor.
__global__ __launch_bounds__(256) void scan_apply_k(const int* __restrict__ cnt,
                                                    const int* __restrict__ bsum_excl, int N,
                                                    int* __restrict__ rowptr,
                                                    int* __restrict__ cursor, int E) {
  __shared__ int wave_sums[4];
  int b = blockIdx.x, t = threadIdx.x;
  int base = b * SCAN_CHUNK + t * 8;
  int v[8];
  int s = 0;
#pragma unroll
  for (int i = 0; i < 8; ++i) {
    int idx = base + i;
    v[i] = (idx < N) ? cnt[idx] : 0;
    s += v[i];
  }
  int lane = t & 63, wave = t >> 6;
  int ps = s;
  for (int off = 1; off < 64; off <<= 1) {
    int u = __shfl_up(ps, off, 64);
    if (lane >= off) ps += u;
  }
  if (lane == 63) wave_sums[wave] = ps;
  __syncthreads();
  int woff = 0;
  for (int w = 0; w < 4; ++w)
    if (w < wave) woff += wave_sums[w];
  int excl = woff + (ps - s) + bsum_excl[b];
#pragma unroll
  for (int i = 0; i < 8; ++i) {
    int idx = base + i;
    if (idx < N) {
      rowptr[idx] = excl;
      cursor[idx] = excl;
      excl += v[i];
    }
  }
  if (b == 0 && t == 0) rowptr[N] = E;
}

__global__ __launch_bounds__(256) void fill_k(const int* __restrict__ src,
                                              const int* __restrict__ dst, int E,
                                              int* __restrict__ cursor, int* __restrict__ col) {
  int idx = blockIdx.x * blockDim.x + threadIdx.x;
  int stride = gridDim.x * blockDim.x;
  for (int e = idx; e < E; e += stride) {
    int d = dst[e];
    int pos = atomicAdd(&cursor[d], 1);
    col[pos] = src[e];
  }
}

// ---------------------------------------------------------------- GEMMs (fp32, VALU)
template <bool SIG>
__global__ __launch_bounds__(256) void gemm128_k(const float* __restrict__ A,
                                                 const float* __restrict__ W,
                                                 const float* __restrict__ bias,
                                                 float* __restrict__ out, int N) {
  __shared__ float At[64][68];    // [k][row], 17.4 KB
  __shared__ float Wl[64][128];   // 32 KB
  const int tid = threadIdx.x;
  const int r0 = blockIdx.x * 64;
  const int cg = (tid & 31) * 4;  // 32 col-groups x 4 = 128
  const int rg = (tid >> 5) * 8;  // 8 row-groups x 8 = 64
  float acc[8][4];
#pragma unroll
  for (int r = 0; r < 8; ++r)
#pragma unroll
    for (int c = 0; c < 4; ++c) acc[r][c] = 0.f;

  for (int kt = 0; kt < 128; kt += 64) {
    if (kt) __syncthreads();
#pragma unroll
    for (int idx = tid; idx < 1024; idx += 256) {
      int rr = idx >> 4;
      int k4 = (idx & 15) << 2;
      float4 v = make_float4(0.f, 0.f, 0.f, 0.f);
      int grow = r0 + rr;
      if (grow < N) v = *(const float4*)(A + (size_t)grow * 128 + kt + k4);
      At[k4 + 0][rr] = v.x;
      At[k4 + 1][rr] = v.y;
      At[k4 + 2][rr] = v.z;
      At[k4 + 3][rr] = v.w;
    }
#pragma unroll
    for (int idx = tid; idx < 2048; idx += 256) {
      int kk = idx >> 5;
      int c4 = (idx & 31) << 2;
      *(float4*)&Wl[kk][c4] = *(const float4*)(W + (size_t)(kt + kk) * 128 + c4);
    }
    __syncthreads();
#pragma unroll 8
    for (int k = 0; k < 64; ++k) {
      float4 a0 = *(const float4*)&At[k][rg];
      float4 a1 = *(const float4*)&At[k][rg + 4];
      float4 b = *(const float4*)&Wl[k][cg];
      float av[8] = {a0.x, a0.y, a0.z, a0.w, a1.x, a1.y, a1.z, a1.w};
      float bv[4] = {b.x, b.y, b.z, b.w};
#pragma unroll
      for (int r = 0; r < 8; ++r)
#pragma unroll
        for (int c = 0; c < 4; ++c) acc[r][c] = fmaf(av[r], bv[c], acc[r][c]);
    }
  }
  float bv[4] = {0.f, 0.f, 0.f, 0.f};
  if (bias) {
    float4 b4 = *(const float4*)(bias + cg);
    bv[0] = b4.x; bv[1] = b4.y; bv[2] = b4.z; bv[3] = b4.w;
  }
#pragma unroll
  for (int r = 0; r < 8; ++r) {
    int grow = r0 + rg + r;
    if (grow < N) {
      float t0 = acc[r][0] + bv[0];
      float t1 = acc[r][1] + bv[1];
      float t2 = acc[r][2] + bv[2];
      float t3 = acc[r][3] + bv[3];
      if (SIG) {
        t0 = 1.f / (1.f + __expf(-t0));
        t1 = 1.f / (1.f + __expf(-t1));
        t2 = 1.f / (1.f + __expf(-t2));
        t3 = 1.f / (1.f + __expf(-t3));
      }
      *(float4*)(out + (size_t)grow * 128 + cg) = make_float4(t0, t1, t2, t3);
    }
  }
}

__global__ __launch_bounds__(256) void gemm16_k(const float* __restrict__ A,
                                                const float* __restrict__ W,
                                                float* __restrict__ out, int N) {
  __shared__ float At[128][68];  // 34.8 KB
  __shared__ float Wl[128][16];  // 8 KB
  const int tid = threadIdx.x;
  const int r0 = blockIdx.x * 64;
  const int colc = tid & 15;
  const int rowg = (tid >> 4) * 4;
  for (int idx = tid; idx < 2048; idx += 256) {
    int rr = idx >> 5;
    int k4 = (idx & 31) << 2;
    float4 v = make_float4(0.f, 0.f, 0.f, 0.f);
    int grow = r0 + rr;
    if (grow < N) v = *(const float4*)(A + (size_t)grow * 128 + k4);
    At[k4 + 0][rr] = v.x;
    At[k4 + 1][rr] = v.y;
    At[k4 + 2][rr] = v.z;
    At[k4 + 3][rr] = v.w;
  }
  for (int idx = tid; idx < 512; idx += 256) {
    int kk = idx >> 2;
    int c4 = (idx & 3) << 2;
    *(float4*)&Wl[kk][c4] = *(const float4*)(W + (size_t)kk * 16 + c4);
  }
  __syncthreads();
  float acc[4] = {0.f, 0.f, 0.f, 0.f};
#pragma unroll 8
  for (int k = 0; k < 128; ++k) {
    float4 a = *(const float4*)&At[k][rowg];
    float b = Wl[k][colc];
    acc[0] = fmaf(a.x, b, acc[0]);
    acc[1] = fmaf(a.y, b, acc[1]);
    acc[2] = fmaf(a.z, b, acc[2]);
    acc[3] = fmaf(a.w, b, acc[3]);
  }
#pragma unroll
  for (int r = 0; r < 4; ++r) {
    int grow = r0 + rowg + r;
    if (grow < N) out[(size_t)grow * 16 + colc] = acc[r];
  }
}

// ---------------------------------------------------------------- aggregation
__global__ __launch_bounds__(256) void agg128_k(const float* __restrict__ xw,
                                                const int* __restrict__ rowptr,
                                                const int* __restrict__ col,
                                                const float* __restrict__ dinv,
                                                const float* __restrict__ bias,
                                                float* __restrict__ out, int N) {
  int node = blockIdx.x * 4 + (threadIdx.x >> 6);
  if (node >= N) return;
  int lane = threadIdx.x & 63;
  int beg = rowptr[node];
  int end = rowptr[node + 1];
  float di = dinv[node];
  float2 sv = *(const float2*)(xw + (size_t)node * 128 + lane * 2);
  float ax = sv.x * di;
  float ay = sv.y * di;
  for (int e = beg; e < end; ++e) {
    int s = col[e];
    float w = dinv[s];
    float2 v = *(const float2*)(xw + (size_t)s * 128 + lane * 2);
    ax = fmaf(v.x, w, ax);
    ay = fmaf(v.y, w, ay);
  }
  float2 bb = *(const float2*)(bias + lane * 2);
  *(float2*)(out + (size_t)node * 128 + lane * 2) =
      make_float2(fmaf(ax, di, bb.x), fmaf(ay, di, bb.y));
}

__global__ __launch_bounds__(256) void agg16_k(const float* __restrict__ xw,
                                               const int* __restrict__ rowptr,
                                               const int* __restrict__ col,
                                               const float* __restrict__ dinv,
                                               const float* __restrict__ bias,
                                               float* __restrict__ out, int N) {
  int node = blockIdx.x * 4 + (threadIdx.x >> 6);
  if (node >= N) return;
  int lane = threadIdx.x & 63;
  int f = lane & 15;
  int j = lane >> 4;
  int beg = rowptr[node];
  int end = rowptr[node + 1];
  float di = dinv[node];
  float acc = 0.f;
  for (int e = beg + j; e < end; e += 4) {
    int s = col[e];
    acc = fmaf(xw[(size_t)s * 16 + f], dinv[s], acc);
  }
  acc += __shfl_xor(acc, 16, 64);
  acc += __shfl_xor(acc, 32, 64);
  float o = fmaf(acc + xw[(size_t)node * 16 + f] * di, di, bias[f]);
  if (j == 0) out[(size_t)node * 16 + f] = o;
}

// ---------------------------------------------------------------- launch
extern "C" void kernel_launch(void* const* d_in, const int* in_sizes, int n_in,
                              void* d_out, int out_size, void* d_ws, size_t ws_size,
                              hipStream_t stream) {
  const int* adj = (const int*)d_in[0];
  const float* X = (const float*)d_in[1];
  const float* fc1_W = (const float*)d_in[2];
  const float* fc1_b = (const float*)d_in[3];
  const float* fc2_W = (const float*)d_in[4];
  const float* fc2_b = (const float*)d_in[5];
  const float* gcn_W = (const float*)d_in[6];
  const float* gcn_b = (const float*)d_in[7];
  const float* assign_W = (const float*)d_in[8];
  const float* assign_b = (const float*)d_in[9];
  const int E = in_sizes[0] / 2;
  const int N = in_sizes[1] / 128;
  const int* src = adj;
  const int* dst = adj + E;

  char* ws = (char*)d_ws;
  size_t off = 0;
  auto alloc = [&](size_t bytes) {
    void* p = ws + off;
    off = (off + bytes + 511) & ~(size_t)511;
    return p;
  };
  float* P = (float*)alloc((size_t)N * 128 * 4);      // 51.2 MB
  float* Q = (float*)alloc((size_t)N * 128 * 4);      // 51.2 MB
  int* cnt = (int*)alloc((size_t)N * 4);
  float* dinv = (float*)alloc((size_t)N * 4);
  int* rowptr = (int*)alloc((size_t)(N + 1) * 4);
  int* cursor = (int*)alloc((size_t)N * 4);
  int* col = (int*)alloc((size_t)E * 4);              // 6.4 MB
  int* bsum = (int*)alloc(4096);
  float* S = P;  // assign xw [N,16] reuses P (free by then)

  const int NB = (N + SCAN_CHUNK - 1) / SCAN_CHUNK;

  hipMemsetAsync(cnt, 0, (size_t)N * 4, stream);
  count_edges_k<<<2048, 256, 0, stream>>>(dst, E, cnt);
  dinv_k<<<(N + 255) / 256, 256, 0, stream>>>(cnt, dinv, N);
  scan_partial_k<<<NB, 256, 0, stream>>>(cnt, N, bsum);
  scan_bsum_k<<<1, 64, 0, stream>>>(bsum, NB);
  scan_apply_k<<<NB, 256, 0, stream>>>(cnt, bsum, N, rowptr, cursor, E);
  fill_k<<<2048, 256, 0, stream>>>(src, dst, E, cursor, col);

  int gb = (N + 63) / 64;
  int ab = (N + 3) / 4;
  gemm128_k<true><<<gb, 256, 0, stream>>>(X, fc1_W, fc1_b, P, N);
  gemm128_k<true><<<gb, 256, 0, stream>>>(P, fc2_W, fc2_b, Q, N);
  for (int l = 0; l < 3; ++l) {
    gemm128_k<false><<<gb, 256, 0, stream>>>(Q, gcn_W + (size_t)l * 128 * 128, nullptr, P, N);
    agg128_k<<<ab, 256, 0, stream>>>(P, rowptr, col, dinv, gcn_b + (size_t)l * 128, Q, N);
  }
  gemm16_k<<<gb, 256, 0, stream>>>(Q, assign_W, S, N);
  agg16_k<<<ab, 256, 0, stream>>>(S, rowptr, col, dinv, assign_b, (float*)d_out, N);
}

// Round 3
// 954.487 us; speedup vs baseline: 1.4234x; 1.2203x over previous
//
#include <hip/hip_runtime.h>
#include <cstdint>
#include <cstddef>

// GraphCluster: 3-layer GCN + assign head, 100K nodes / 1.6M edges.
// R1: hierarchical scan. R2: f16-MFMA GEMMs (fp32 io/accum), dinv folded into
// GEMM epilogue, agg edge-loop unrolled 4x for MLP.

#define SCAN_CHUNK 2048

typedef _Float16 half8 __attribute__((ext_vector_type(8)));
typedef float floatx4 __attribute__((ext_vector_type(4)));

// ---------------------------------------------------------------- CSR build
__global__ __launch_bounds__(256) void count_edges_k(const int* __restrict__ dst, int E,
                                                     int* __restrict__ cnt) {
  int idx = blockIdx.x * blockDim.x + threadIdx.x;
  int stride = gridDim.x * blockDim.x;
  for (int e = idx; e < E; e += stride) atomicAdd(&cnt[dst[e]], 1);
}

__global__ __launch_bounds__(256) void dinv_k(const int* __restrict__ cnt,
                                              float* __restrict__ dinv, int N) {
  int i = blockIdx.x * blockDim.x + threadIdx.x;
  if (i < N) dinv[i] = rsqrtf((float)(cnt[i] + 1));  // +1 self-loop
}

__global__ __launch_bounds__(256) void scan_partial_k(const int* __restrict__ cnt, int N,
                                                      int* __restrict__ bsum) {
  __shared__ int red[256];
  int b = blockIdx.x, t = threadIdx.x;
  int base = b * SCAN_CHUNK + t * 8;
  int s = 0;
#pragma unroll
  for (int i = 0; i < 8; ++i) {
    int idx = base + i;
    if (idx < N) s += cnt[idx];
  }
  red[t] = s;
  __syncthreads();
  for (int off = 128; off > 0; off >>= 1) {
    if (t < off) red[t] += red[t + off];
    __syncthreads();
  }
  if (t == 0) bsum[b] = red[0];
}

__global__ __launch_bounds__(64) void scan_bsum_k(int* __restrict__ bsum, int NB) {
  int lane = threadIdx.x;
  int per = (NB + 63) >> 6;
  int beg = lane * per;
  int end = min(beg + per, NB);
  int s = 0;
  for (int i = beg; i < end; ++i) s += bsum[i];
  int ps = s;
  for (int off = 1; off < 64; off <<= 1) {
    int u = __shfl_up(ps, off, 64);
    if (lane >= off) ps += u;
  }
  int run = ps - s;
  for (int i = beg; i < end; ++i) {
    int c = bsum[i];
    bsum[i] = run;
    run += c;
  }
}

__global__ __launch_bounds__(256) void scan_apply_k(const int* __restrict__ cnt,
                                                    const int* __restrict__ bsum_excl, int N,
                                                    int* __restrict__ rowptr,
                                                    int* __restrict__ cursor, int E) {
  __shared__ int wave_sums[4];
  int b = blockIdx.x, t = threadIdx.x;
  int base = b * SCAN_CHUNK + t * 8;
  int v[8];
  int s = 0;
#pragma unroll
  for (int i = 0; i < 8; ++i) {
    int idx = base + i;
    v[i] = (idx < N) ? cnt[idx] : 0;
    s += v[i];
  }
  int lane = t & 63, wave = t >> 6;
  int ps = s;
  for (int off = 1; off < 64; off <<= 1) {
    int u = __shfl_up(ps, off, 64);
    if (lane >= off) ps += u;
  }
  if (lane == 63) wave_sums[wave] = ps;
  __syncthreads();
  int woff = 0;
  for (int w = 0; w < 4; ++w)
    if (w < wave) woff += wave_sums[w];
  int excl = woff + (ps - s) + bsum_excl[b];
#pragma unroll
  for (int i = 0; i < 8; ++i) {
    int idx = base + i;
    if (idx < N) {
      rowptr[idx] = excl;
      cursor[idx] = excl;
      excl += v[i];
    }
  }
  if (b == 0 && t == 0) rowptr[N] = E;
}

__global__ __launch_bounds__(256) void fill_k(const int* __restrict__ src,
                                              const int* __restrict__ dst, int E,
                                              int* __restrict__ cursor, int* __restrict__ col) {
  int idx = blockIdx.x * blockDim.x + threadIdx.x;
  int stride = gridDim.x * blockDim.x;
  for (int e = idx; e < E; e += stride) {
    int d = dst[e];
    int pos = atomicAdd(&cursor[d], 1);
    col[pos] = src[e];
  }
}

// ---------------------------------------------------------------- f16 MFMA GEMM
// out[N,NCOL] = A[N,128] @ W[128,NCOL]; optional +bias, sigmoid, *scale[row].
// Block: 256 thr (4 waves), 64-row tile, full K=128. LDS staged as f16 with
// pad-8 (row stride 272B -> 2-way bank alias only, free).
template <bool SIG, int NT>  // NT = # of 16-col tiles (8 -> 128 cols, 1 -> 16)
__global__ __launch_bounds__(256) void gemm_mfma_k(const float* __restrict__ A,
                                                   const float* __restrict__ W,
                                                   const float* __restrict__ bias,
                                                   const float* __restrict__ scale,
                                                   float* __restrict__ out, int N) {
  constexpr int NCOL = NT * 16;
  __shared__ __align__(16) _Float16 Af[64][136];
  __shared__ __align__(16) _Float16 Wf[NCOL][136];
  const int tid = threadIdx.x;
  const int r0 = blockIdx.x * 64;
  // stage A (fp32 -> f16), row-major [row][k]
  for (int idx = tid; idx < 64 * 32; idx += 256) {
    int row = idx >> 5;
    int c4 = (idx & 31) << 2;
    float4 v = make_float4(0.f, 0.f, 0.f, 0.f);
    int gr = r0 + row;
    if (gr < N) v = *(const float4*)(A + (size_t)gr * 128 + c4);
    Af[row][c4 + 0] = (_Float16)v.x;
    Af[row][c4 + 1] = (_Float16)v.y;
    Af[row][c4 + 2] = (_Float16)v.z;
    Af[row][c4 + 3] = (_Float16)v.w;
  }
  // stage W transposed: Wf[n][k] = W[k][n]
  for (int idx = tid; idx < 128 * (NCOL / 4); idx += 256) {
    int k = idx / (NCOL / 4);
    int n4 = (idx % (NCOL / 4)) << 2;
    float4 v = *(const float4*)(W + (size_t)k * NCOL + n4);
    Wf[n4 + 0][k] = (_Float16)v.x;
    Wf[n4 + 1][k] = (_Float16)v.y;
    Wf[n4 + 2][k] = (_Float16)v.z;
    Wf[n4 + 3][k] = (_Float16)v.w;
  }
  __syncthreads();
  const int w = tid >> 6, lane = tid & 63;
  const int m = lane & 15, q = lane >> 4;
  floatx4 acc[NT];
#pragma unroll
  for (int t = 0; t < NT; ++t) acc[t] = (floatx4){0.f, 0.f, 0.f, 0.f};
#pragma unroll
  for (int kt = 0; kt < 128; kt += 32) {
    half8 a = *(const half8*)&Af[w * 16 + m][kt + q * 8];
#pragma unroll
    for (int t = 0; t < NT; ++t) {
      half8 b = *(const half8*)&Wf[t * 16 + m][kt + q * 8];
      acc[t] = __builtin_amdgcn_mfma_f32_16x16x32_f16(a, b, acc[t], 0, 0, 0);
    }
  }
  // epilogue: C/D layout col=lane&15, row=q*4+reg
#pragma unroll
  for (int r = 0; r < 4; ++r) {
    int row = r0 + w * 16 + q * 4 + r;
    if (row >= N) continue;
    float sc = scale ? scale[row] : 1.f;
#pragma unroll
    for (int t = 0; t < NT; ++t) {
      int colg = t * 16 + m;
      float v = acc[t][r];
      if (bias) v += bias[colg];
      if (SIG) v = 1.f / (1.f + __expf(-v));
      out[(size_t)row * NCOL + colg] = v * sc;
    }
  }
}

// ---------------------------------------------------------------- aggregation
// xw is PRE-SCALED by dinv[row] in the GEMM epilogue:
// out[i] = bias + dinv[i] * ( xw[i] + sum_{e: dst=i} xw[src_e] )
__global__ __launch_bounds__(256) void agg128_k(const float* __restrict__ xw,
                                                const int* __restrict__ rowptr,
                                                const int* __restrict__ col,
                                                const float* __restrict__ dinv,
                                                const float* __restrict__ bias,
                                                float* __restrict__ out, int N) {
  int node = blockIdx.x * 4 + (threadIdx.x >> 6);
  if (node >= N) return;
  int lane = threadIdx.x & 63;
  int beg = rowptr[node];
  int end = rowptr[node + 1];
  const float* base = xw + (size_t)lane * 2;
  float2 sv = *(const float2*)(base + (size_t)node * 128);
  float ax = sv.x, ay = sv.y;
  int e = beg;
  for (; e + 4 <= end; e += 4) {
    int s0 = col[e], s1 = col[e + 1], s2 = col[e + 2], s3 = col[e + 3];
    float2 v0 = *(const float2*)(base + (size_t)s0 * 128);
    float2 v1 = *(const float2*)(base + (size_t)s1 * 128);
    float2 v2 = *(const float2*)(base + (size_t)s2 * 128);
    float2 v3 = *(const float2*)(base + (size_t)s3 * 128);
    ax += (v0.x + v1.x) + (v2.x + v3.x);
    ay += (v0.y + v1.y) + (v2.y + v3.y);
  }
  for (; e < end; ++e) {
    int s = col[e];
    float2 v = *(const float2*)(base + (size_t)s * 128);
    ax += v.x;
    ay += v.y;
  }
  float di = dinv[node];
  float2 bb = *(const float2*)(bias + lane * 2);
  *(float2*)(out + (size_t)node * 128 + lane * 2) =
      make_float2(fmaf(ax, di, bb.x), fmaf(ay, di, bb.y));
}

__global__ __launch_bounds__(256) void agg16_k(const float* __restrict__ xw,
                                               const int* __restrict__ rowptr,
                                               const int* __restrict__ col,
                                               const float* __restrict__ dinv,
                                               const float* __restrict__ bias,
                                               float* __restrict__ out, int N) {
  int node = blockIdx.x * 4 + (threadIdx.x >> 6);
  if (node >= N) return;
  int lane = threadIdx.x & 63;
  int f = lane & 15;
  int j = lane >> 4;
  int beg = rowptr[node];
  int end = rowptr[node + 1];
  float acc = 0.f;
  for (int e = beg + j; e < end; e += 4) {
    acc += xw[(size_t)col[e] * 16 + f];
  }
  acc += __shfl_xor(acc, 16, 64);
  acc += __shfl_xor(acc, 32, 64);
  float o = fmaf(acc + xw[(size_t)node * 16 + f], dinv[node], bias[f]);
  if (j == 0) out[(size_t)node * 16 + f] = o;
}

// ---------------------------------------------------------------- launch
extern "C" void kernel_launch(void* const* d_in, const int* in_sizes, int n_in,
                              void* d_out, int out_size, void* d_ws, size_t ws_size,
                              hipStream_t stream) {
  const int* adj = (const int*)d_in[0];
  const float* X = (const float*)d_in[1];
  const float* fc1_W = (const float*)d_in[2];
  const float* fc1_b = (const float*)d_in[3];
  const float* fc2_W = (const float*)d_in[4];
  const float* fc2_b = (const float*)d_in[5];
  const float* gcn_W = (const float*)d_in[6];
  const float* gcn_b = (const float*)d_in[7];
  const float* assign_W = (const float*)d_in[8];
  const float* assign_b = (const float*)d_in[9];
  const int E = in_sizes[0] / 2;
  const int N = in_sizes[1] / 128;
  const int* src = adj;
  const int* dst = adj + E;

  char* ws = (char*)d_ws;
  size_t off = 0;
  auto alloc = [&](size_t bytes) {
    void* p = ws + off;
    off = (off + bytes + 511) & ~(size_t)511;
    return p;
  };
  float* P = (float*)alloc((size_t)N * 128 * 4);
  float* Q = (float*)alloc((size_t)N * 128 * 4);
  int* cnt = (int*)alloc((size_t)N * 4);
  float* dinv = (float*)alloc((size_t)N * 4);
  int* rowptr = (int*)alloc((size_t)(N + 1) * 4);
  int* cursor = (int*)alloc((size_t)N * 4);
  int* col = (int*)alloc((size_t)E * 4);
  int* bsum = (int*)alloc(4096);
  float* S = P;  // assign xw [N,16] reuses P

  const int NB = (N + SCAN_CHUNK - 1) / SCAN_CHUNK;

  hipMemsetAsync(cnt, 0, (size_t)N * 4, stream);
  count_edges_k<<<2048, 256, 0, stream>>>(dst, E, cnt);
  dinv_k<<<(N + 255) / 256, 256, 0, stream>>>(cnt, dinv, N);
  scan_partial_k<<<NB, 256, 0, stream>>>(cnt, N, bsum);
  scan_bsum_k<<<1, 64, 0, stream>>>(bsum, NB);
  scan_apply_k<<<NB, 256, 0, stream>>>(cnt, bsum, N, rowptr, cursor, E);
  fill_k<<<2048, 256, 0, stream>>>(src, dst, E, cursor, col);

  int gb = (N + 63) / 64;
  int ab = (N + 3) / 4;
  gemm_mfma_k<true, 8><<<gb, 256, 0, stream>>>(X, fc1_W, fc1_b, nullptr, P, N);
  gemm_mfma_k<true, 8><<<gb, 256, 0, stream>>>(P, fc2_W, fc2_b, nullptr, Q, N);
  for (int l = 0; l < 3; ++l) {
    gemm_mfma_k<false, 8><<<gb, 256, 0, stream>>>(Q, gcn_W + (size_t)l * 128 * 128, nullptr,
                                                  dinv, P, N);
    agg128_k<<<ab, 256, 0, stream>>>(P, rowptr, col, dinv, gcn_b + (size_t)l * 128, Q, N);
  }
  gemm_mfma_k<false, 1><<<gb, 256, 0, stream>>>(Q, assign_W, nullptr, dinv, S, N);
  agg16_k<<<ab, 256, 0, stream>>>(S, rowptr, col, dinv, assign_b, (float*)d_out, N);
}

// Round 4
// 775.856 us; speedup vs baseline: 1.7511x; 1.2302x over previous
//
#include <hip/hip_runtime.h>
#include <cstdint>
#include <cstddef>

// GraphCluster: 3-layer GCN + assign head, 100K nodes / 1.6M edges.
// R1: hierarchical scan. R2: f16-MFMA GEMMs, dinv folded into GEMM epilogue.
// R3: f16 intermediate pipeline (halves GEMM+agg traffic), agg 2-edge lanes.

#define SCAN_CHUNK 2048

typedef _Float16 half8 __attribute__((ext_vector_type(8)));
typedef _Float16 half4 __attribute__((ext_vector_type(4)));
typedef float floatx4 __attribute__((ext_vector_type(4)));

// ---------------------------------------------------------------- CSR build
__global__ __launch_bounds__(256) void count_edges_k(const int* __restrict__ dst, int E,
                                                     int* __restrict__ cnt) {
  int idx = blockIdx.x * blockDim.x + threadIdx.x;
  int stride = gridDim.x * blockDim.x;
  for (int e = idx; e < E; e += stride) atomicAdd(&cnt[dst[e]], 1);
}

__global__ __launch_bounds__(256) void dinv_k(const int* __restrict__ cnt,
                                              float* __restrict__ dinv, int N) {
  int i = blockIdx.x * blockDim.x + threadIdx.x;
  if (i < N) dinv[i] = rsqrtf((float)(cnt[i] + 1));  // +1 self-loop
}

__global__ __launch_bounds__(256) void scan_partial_k(const int* __restrict__ cnt, int N,
                                                      int* __restrict__ bsum) {
  __shared__ int red[256];
  int b = blockIdx.x, t = threadIdx.x;
  int base = b * SCAN_CHUNK + t * 8;
  int s = 0;
#pragma unroll
  for (int i = 0; i < 8; ++i) {
    int idx = base + i;
    if (idx < N) s += cnt[idx];
  }
  red[t] = s;
  __syncthreads();
  for (int off = 128; off > 0; off >>= 1) {
    if (t < off) red[t] += red[t + off];
    __syncthreads();
  }
  if (t == 0) bsum[b] = red[0];
}

__global__ __launch_bounds__(64) void scan_bsum_k(int* __restrict__ bsum, int NB) {
  int lane = threadIdx.x;
  int per = (NB + 63) >> 6;
  int beg = lane * per;
  int end = min(beg + per, NB);
  int s = 0;
  for (int i = beg; i < end; ++i) s += bsum[i];
  int ps = s;
  for (int off = 1; off < 64; off <<= 1) {
    int u = __shfl_up(ps, off, 64);
    if (lane >= off) ps += u;
  }
  int run = ps - s;
  for (int i = beg; i < end; ++i) {
    int c = bsum[i];
    bsum[i] = run;
    run += c;
  }
}

__global__ __launch_bounds__(256) void scan_apply_k(const int* __restrict__ cnt,
                                                    const int* __restrict__ bsum_excl, int N,
                                                    int* __restrict__ rowptr,
                                                    int* __restrict__ cursor, int E) {
  __shared__ int wave_sums[4];
  int b = blockIdx.x, t = threadIdx.x;
  int base = b * SCAN_CHUNK + t * 8;
  int v[8];
  int s = 0;
#pragma unroll
  for (int i = 0; i < 8; ++i) {
    int idx = base + i;
    v[i] = (idx < N) ? cnt[idx] : 0;
    s += v[i];
  }
  int lane = t & 63, wave = t >> 6;
  int ps = s;
  for (int off = 1; off < 64; off <<= 1) {
    int u = __shfl_up(ps, off, 64);
    if (lane >= off) ps += u;
  }
  if (lane == 63) wave_sums[wave] = ps;
  __syncthreads();
  int woff = 0;
  for (int w = 0; w < 4; ++w)
    if (w < wave) woff += wave_sums[w];
  int excl = woff + (ps - s) + bsum_excl[b];
#pragma unroll
  for (int i = 0; i < 8; ++i) {
    int idx = base + i;
    if (idx < N) {
      rowptr[idx] = excl;
      cursor[idx] = excl;
      excl += v[i];
    }
  }
  if (b == 0 && t == 0) rowptr[N] = E;
}

__global__ __launch_bounds__(256) void fill_k(const int* __restrict__ src,
                                              const int* __restrict__ dst, int E,
                                              int* __restrict__ cursor, int* __restrict__ col) {
  int idx = blockIdx.x * blockDim.x + threadIdx.x;
  int stride = gridDim.x * blockDim.x;
  for (int e = idx; e < E; e += stride) {
    int d = dst[e];
    int pos = atomicAdd(&cursor[d], 1);
    col[pos] = src[e];
  }
}

// ---------------------------------------------------------------- f16 MFMA GEMM
// out[N,NCOL] = A[N,128] @ W[128,NCOL]; optional +bias, sigmoid, *scale[row].
// A: f16 (HIN) or fp32; out: f16 (HOUT) or fp32. LDS pad 8 f16 -> 2-way bank
// alias only (free).
template <bool SIG, bool HIN, bool HOUT, int NT>
__global__ __launch_bounds__(256) void gemm_mfma_k(const void* __restrict__ Av,
                                                   const float* __restrict__ W,
                                                   const float* __restrict__ bias,
                                                   const float* __restrict__ scale,
                                                   void* __restrict__ outv, int N) {
  constexpr int NCOL = NT * 16;
  __shared__ __align__(16) _Float16 Af[64][136];
  __shared__ __align__(16) _Float16 Wf[NCOL][136];
  const int tid = threadIdx.x;
  const int r0 = blockIdx.x * 64;
  if (HIN) {
    const _Float16* A = (const _Float16*)Av;
    for (int idx = tid; idx < 64 * 16; idx += 256) {
      int row = idx >> 4;
      int c8 = (idx & 15) << 3;
      half8 v = {0, 0, 0, 0, 0, 0, 0, 0};
      int gr = r0 + row;
      if (gr < N) v = *(const half8*)(A + (size_t)gr * 128 + c8);
      *(half8*)&Af[row][c8] = v;
    }
  } else {
    const float* A = (const float*)Av;
    for (int idx = tid; idx < 64 * 32; idx += 256) {
      int row = idx >> 5;
      int c4 = (idx & 31) << 2;
      float4 v = make_float4(0.f, 0.f, 0.f, 0.f);
      int gr = r0 + row;
      if (gr < N) v = *(const float4*)(A + (size_t)gr * 128 + c4);
      Af[row][c4 + 0] = (_Float16)v.x;
      Af[row][c4 + 1] = (_Float16)v.y;
      Af[row][c4 + 2] = (_Float16)v.z;
      Af[row][c4 + 3] = (_Float16)v.w;
    }
  }
  // stage W transposed: Wf[n][k] = W[k][n]
  for (int idx = tid; idx < 128 * (NCOL / 4); idx += 256) {
    int k = idx / (NCOL / 4);
    int n4 = (idx % (NCOL / 4)) << 2;
    float4 v = *(const float4*)(W + (size_t)k * NCOL + n4);
    Wf[n4 + 0][k] = (_Float16)v.x;
    Wf[n4 + 1][k] = (_Float16)v.y;
    Wf[n4 + 2][k] = (_Float16)v.z;
    Wf[n4 + 3][k] = (_Float16)v.w;
  }
  __syncthreads();
  const int w = tid >> 6, lane = tid & 63;
  const int m = lane & 15, q = lane >> 4;
  floatx4 acc[NT];
#pragma unroll
  for (int t = 0; t < NT; ++t) acc[t] = (floatx4){0.f, 0.f, 0.f, 0.f};
#pragma unroll
  for (int kt = 0; kt < 128; kt += 32) {
    half8 a = *(const half8*)&Af[w * 16 + m][kt + q * 8];
#pragma unroll
    for (int t = 0; t < NT; ++t) {
      half8 b = *(const half8*)&Wf[t * 16 + m][kt + q * 8];
      acc[t] = __builtin_amdgcn_mfma_f32_16x16x32_f16(a, b, acc[t], 0, 0, 0);
    }
  }
  // epilogue: C/D layout col=lane&15, row=q*4+reg
#pragma unroll
  for (int r = 0; r < 4; ++r) {
    int row = r0 + w * 16 + q * 4 + r;
    if (row >= N) continue;
    float sc = scale ? scale[row] : 1.f;
#pragma unroll
    for (int t = 0; t < NT; ++t) {
      int colg = t * 16 + m;
      float v = acc[t][r];
      if (bias) v += bias[colg];
      if (SIG) v = 1.f / (1.f + __expf(-v));
      v *= sc;
      if (HOUT)
        ((_Float16*)outv)[(size_t)row * NCOL + colg] = (_Float16)v;
      else
        ((float*)outv)[(size_t)row * NCOL + colg] = v;
    }
  }
}

// ---------------------------------------------------------------- aggregation
// xw (f16) is PRE-SCALED by dinv[row]: out[i] = b + dinv[i]*(xw[i]+sum xw[src]).
// One wave/node; 32 lanes x half4 cover the 128-dim row; 2 edges in flight per
// iteration (j = lane>>5), unrolled 4x -> 8 gathers outstanding.
__global__ __launch_bounds__(256) void agg128h_k(const _Float16* __restrict__ xw,
                                                 const int* __restrict__ rowptr,
                                                 const int* __restrict__ col,
                                                 const float* __restrict__ dinv,
                                                 const float* __restrict__ bias,
                                                 _Float16* __restrict__ out, int N) {
  int node = blockIdx.x * 4 + (threadIdx.x >> 6);
  if (node >= N) return;
  int lane = threadIdx.x & 63;
  int fl = lane & 31;  // feature chunk (4 f16)
  int j = lane >> 5;   // edge parity
  int beg = rowptr[node];
  int end = rowptr[node + 1];
  const _Float16* base = xw + (size_t)fl * 4;
  float a0 = 0.f, a1 = 0.f, a2 = 0.f, a3 = 0.f;
  int e = beg + j;
  for (; e + 6 < end; e += 8) {
    int s0 = col[e], s1 = col[e + 2], s2 = col[e + 4], s3 = col[e + 6];
    half4 v0 = *(const half4*)(base + (size_t)s0 * 128);
    half4 v1 = *(const half4*)(base + (size_t)s1 * 128);
    half4 v2 = *(const half4*)(base + (size_t)s2 * 128);
    half4 v3 = *(const half4*)(base + (size_t)s3 * 128);
    a0 += ((float)v0[0] + (float)v1[0]) + ((float)v2[0] + (float)v3[0]);
    a1 += ((float)v0[1] + (float)v1[1]) + ((float)v2[1] + (float)v3[1]);
    a2 += ((float)v0[2] + (float)v1[2]) + ((float)v2[2] + (float)v3[2]);
    a3 += ((float)v0[3] + (float)v1[3]) + ((float)v2[3] + (float)v3[3]);
  }
  for (; e < end; e += 2) {
    half4 v = *(const half4*)(base + (size_t)col[e] * 128);
    a0 += (float)v[0];
    a1 += (float)v[1];
    a2 += (float)v[2];
    a3 += (float)v[3];
  }
  if (j == 0) {  // self-loop term once
    half4 v = *(const half4*)(base + (size_t)node * 128);
    a0 += (float)v[0];
    a1 += (float)v[1];
    a2 += (float)v[2];
    a3 += (float)v[3];
  }
  a0 += __shfl_xor(a0, 32, 64);
  a1 += __shfl_xor(a1, 32, 64);
  a2 += __shfl_xor(a2, 32, 64);
  a3 += __shfl_xor(a3, 32, 64);
  if (j == 0) {
    float di = dinv[node];
    float4 bb = *(const float4*)(bias + fl * 4);
    half4 o;
    o[0] = (_Float16)fmaf(a0, di, bb.x);
    o[1] = (_Float16)fmaf(a1, di, bb.y);
    o[2] = (_Float16)fmaf(a2, di, bb.z);
    o[3] = (_Float16)fmaf(a3, di, bb.w);
    *(half4*)(out + (size_t)node * 128 + fl * 4) = o;
  }
}

__global__ __launch_bounds__(256) void agg16_k(const float* __restrict__ xw,
                                               const int* __restrict__ rowptr,
                                               const int* __restrict__ col,
                                               const float* __restrict__ dinv,
                                               const float* __restrict__ bias,
                                               float* __restrict__ out, int N) {
  int node = blockIdx.x * 4 + (threadIdx.x >> 6);
  if (node >= N) return;
  int lane = threadIdx.x & 63;
  int f = lane & 15;
  int j = lane >> 4;
  int beg = rowptr[node];
  int end = rowptr[node + 1];
  float acc = 0.f;
  for (int e = beg + j; e < end; e += 4) {
    acc += xw[(size_t)col[e] * 16 + f];
  }
  acc += __shfl_xor(acc, 16, 64);
  acc += __shfl_xor(acc, 32, 64);
  float o = fmaf(acc + xw[(size_t)node * 16 + f], dinv[node], bias[f]);
  if (j == 0) out[(size_t)node * 16 + f] = o;
}

// ---------------------------------------------------------------- launch
extern "C" void kernel_launch(void* const* d_in, const int* in_sizes, int n_in,
                              void* d_out, int out_size, void* d_ws, size_t ws_size,
                              hipStream_t stream) {
  const int* adj = (const int*)d_in[0];
  const float* X = (const float*)d_in[1];
  const float* fc1_W = (const float*)d_in[2];
  const float* fc1_b = (const float*)d_in[3];
  const float* fc2_W = (const float*)d_in[4];
  const float* fc2_b = (const float*)d_in[5];
  const float* gcn_W = (const float*)d_in[6];
  const float* gcn_b = (const float*)d_in[7];
  const float* assign_W = (const float*)d_in[8];
  const float* assign_b = (const float*)d_in[9];
  const int E = in_sizes[0] / 2;
  const int N = in_sizes[1] / 128;
  const int* src = adj;
  const int* dst = adj + E;

  char* ws = (char*)d_ws;
  size_t off = 0;
  auto alloc = [&](size_t bytes) {
    void* p = ws + off;
    off = (off + bytes + 511) & ~(size_t)511;
    return p;
  };
  _Float16* Ph = (_Float16*)alloc((size_t)N * 128 * 2);  // 25.6 MB
  _Float16* Qh = (_Float16*)alloc((size_t)N * 128 * 2);  // 25.6 MB
  int* cnt = (int*)alloc((size_t)N * 4);
  float* dinv = (float*)alloc((size_t)N * 4);
  int* rowptr = (int*)alloc((size_t)(N + 1) * 4);
  int* cursor = (int*)alloc((size_t)N * 4);
  int* col = (int*)alloc((size_t)E * 4);
  int* bsum = (int*)alloc(4096);
  float* S = (float*)Ph;  // assign xw [N,16] fp32 reuses Ph (free by then)

  const int NB = (N + SCAN_CHUNK - 1) / SCAN_CHUNK;

  hipMemsetAsync(cnt, 0, (size_t)N * 4, stream);
  count_edges_k<<<2048, 256, 0, stream>>>(dst, E, cnt);
  dinv_k<<<(N + 255) / 256, 256, 0, stream>>>(cnt, dinv, N);
  scan_partial_k<<<NB, 256, 0, stream>>>(cnt, N, bsum);
  scan_bsum_k<<<1, 64, 0, stream>>>(bsum, NB);
  scan_apply_k<<<NB, 256, 0, stream>>>(cnt, bsum, N, rowptr, cursor, E);
  fill_k<<<2048, 256, 0, stream>>>(src, dst, E, cursor, col);

  int gb = (N + 63) / 64;
  int ab = (N + 3) / 4;
  gemm_mfma_k<true, false, true, 8><<<gb, 256, 0, stream>>>(X, fc1_W, fc1_b, nullptr, Ph, N);
  gemm_mfma_k<true, true, true, 8><<<gb, 256, 0, stream>>>(Ph, fc2_W, fc2_b, nullptr, Qh, N);
  for (int l = 0; l < 3; ++l) {
    gemm_mfma_k<false, true, true, 8><<<gb, 256, 0, stream>>>(
        Qh, gcn_W + (size_t)l * 128 * 128, nullptr, dinv, Ph, N);
    agg128h_k<<<ab, 256, 0, stream>>>(Ph, rowptr, col, dinv, gcn_b + (size_t)l * 128, Qh, N);
  }
  gemm_mfma_k<false, true, false, 1><<<gb, 256, 0, stream>>>(Qh, assign_W, nullptr, dinv, S, N);
  agg16_k<<<ab, 256, 0, stream>>>(S, rowptr, col, dinv, assign_b, (float*)d_out, N);
}